// Round 15
// baseline (538.387 us; speedup 1.0000x reference)
//
#include <hip/hip_runtime.h>
#include <math.h>

#define BB 4
#define TT 24
#define BN 1024
#define FD 128
#define BT (BB*TT)
#define BTN (BT*BN)
#define FRONT_T 12
#define SCALE 0.08838834764831845f   // 1/sqrt(128)
#define GELU_K 0.7071067811865476f   // 1/sqrt(2)

typedef __attribute__((ext_vector_type(8))) short s8v;   // 8 bf16 (4 VGPRs)
typedef __attribute__((ext_vector_type(4))) float f4v;   // 4 fp32 acc

static __device__ __forceinline__ unsigned short f2bf(float f) {
    union { float f; unsigned u; } c; c.f = f;
    unsigned u = c.u + 0x7FFFu + ((c.u >> 16) & 1u);   // RNE
    return (unsigned short)(u >> 16);
}

// ---------------------------------------------------------------------------
// W_xff -> bf16.
// ---------------------------------------------------------------------------
__global__ void k_convw(const float* __restrict__ W, unsigned short* __restrict__ wb, int n) {
    int i = blockIdx.x * 256 + threadIdx.x;
    if (i < n) wb[i] = f2bf(W[i]);
}

// ---------------------------------------------------------------------------
// Bulk qkv GEMM in bf16 MFMA. 64-row block computes ALL 6 col-tiles; x is
// staged+converted once per block (validated R13).
// ---------------------------------------------------------------------------
__global__ __launch_bounds__(256, 3) void k_qkv_mfma(
    const float* __restrict__ x, const unsigned short* __restrict__ wb,
    const float* __restrict__ bias,
    unsigned short* __restrict__ qb16, unsigned short* __restrict__ kb16,
    unsigned short* __restrict__ vtb)
{
    __shared__ __attribute__((aligned(16))) unsigned short Xs[64 * 136];
    __shared__ __attribute__((aligned(16))) unsigned short Ws[64 * 136];
    __shared__ __attribute__((aligned(16))) unsigned short Cs[64 * 72];
    const int tid = threadIdx.x;
    const int rowBase = blockIdx.x * 64;
    const int lane = tid & 63, wave = tid >> 6;
    const int lx = lane & 15, quad = lane >> 4;

    // stage Xs once: fp32 -> bf16 (same f2bf as the removed k_convx)
    for (int i = 0; i < 4; ++i) {
        int idx = i * 256 + tid, r = idx >> 4, c8 = idx & 15;
        const float* src = x + (size_t)(rowBase + r) * FD + c8 * 8;
        float4 u0 = *(const float4*)(src);
        float4 u1 = *(const float4*)(src + 4);
        ushort4 h0 = {f2bf(u0.x), f2bf(u0.y), f2bf(u0.z), f2bf(u0.w)};
        ushort4 h1 = {f2bf(u1.x), f2bf(u1.y), f2bf(u1.z), f2bf(u1.w)};
        *(ushort4*)(&Xs[r * 136 + c8 * 8])     = h0;
        *(ushort4*)(&Xs[r * 136 + c8 * 8 + 4]) = h1;
    }

    for (int cb = 0; cb < 6; ++cb) {
        __syncthreads();                     // Xs ready / prev Ws,Cs consumed
        const int colBase = cb * 64;
        for (int i = 0; i < 4; ++i) {
            int idx = i * 256 + tid, r = idx >> 4, c8 = idx & 15;
            *(int4*)(&Ws[r * 136 + c8 * 8]) = *(const int4*)(wb + (size_t)(colBase + r) * FD + c8 * 8);
        }
        __syncthreads();

        f4v acc[4];
        for (int gg = 0; gg < 4; ++gg) acc[gg] = (f4v){0.f, 0.f, 0.f, 0.f};
        for (int t4 = 0; t4 < 4; ++t4) {
            s8v a = *(const s8v*)(&Xs[(wave * 16 + lx) * 136 + t4 * 32 + quad * 8]);
            for (int gg = 0; gg < 4; ++gg) {
                s8v b = *(const s8v*)(&Ws[(gg * 16 + lx) * 136 + t4 * 32 + quad * 8]);
                acc[gg] = __builtin_amdgcn_mfma_f32_16x16x32_bf16(a, b, acc[gg], 0, 0, 0);
            }
        }

        const int n0 = wave * 16 + quad * 4;          // C rows (n_local)
        if (colBase < 2 * FD) {
            for (int gg = 0; gg < 4; ++gg) {
                float bb = bias[colBase + gg * 16 + lx];
                for (int r = 0; r < 4; ++r)
                    Cs[(n0 + r) * 72 + gg * 16 + lx] = f2bf(acc[gg][r] + bb);
            }
            __syncthreads();
            unsigned short* dst = (colBase < FD) ? qb16 : kb16;
            const int cc0 = colBase & (FD - 1);
            for (int i = 0; i < 2; ++i) {
                int idx = i * 256 + tid, r = idx >> 3, c8 = idx & 7;
                *(int4*)(dst + (size_t)(rowBase + r) * FD + cc0 + c8 * 8) =
                    *(const int4*)(&Cs[r * 72 + c8 * 8]);
            }
        } else {
            for (int gg = 0; gg < 4; ++gg) {
                float bb = bias[colBase + gg * 16 + lx];
                for (int r = 0; r < 4; ++r)
                    Cs[(gg * 16 + lx) * 72 + n0 + r] = f2bf(acc[gg][r] + bb);
            }
            __syncthreads();
            const int bt = rowBase >> 10, nBase = rowBase & 1023, cc0 = colBase - 2 * FD;
            for (int i = 0; i < 2; ++i) {
                int idx = i * 256 + tid, f = idx >> 3, c8 = idx & 7;
                *(int4*)(vtb + ((size_t)bt * FD + cc0 + f) * BN + nBase + c8 * 8) =
                    *(const int4*)(&Cs[f * 72 + c8 * 8]);
            }
        }
    }
}

// ---------------------------------------------------------------------------
// Exact fp32 GEMM (round-1 verbatim arithmetic) for the bt%24==23 slices
// only -> q32c/k32c bitwise identical to the round-1/4 y_last path.
// ---------------------------------------------------------------------------
__global__ __launch_bounds__(256) void k_qkv32(const float* __restrict__ x,
                                               const float* __restrict__ W,
                                               const float* __restrict__ bias,
                                               float* __restrict__ q32c,
                                               float* __restrict__ k32c) {
    __shared__ float Xs[32][129];
    __shared__ float Ws[64][129];
    const int tid = threadIdx.x;
    const int b = blockIdx.x >> 5;
    const int rt = blockIdx.x & 31;
    const int xrow0 = (b * TT + (TT - 1)) * BN + rt * 32;
    const int colBase = blockIdx.y * 64;      // 0..192 (q,k cols only)

    for (int i = 0; i < 4; ++i) {
        int idx = i * 256 + tid;
        int r = idx >> 5, c4 = idx & 31;
        *(float4*)(&Xs[r][c4 * 4]) = *(const float4*)(x + (size_t)(xrow0 + r) * FD + c4 * 4);
    }
    for (int i = 0; i < 8; ++i) {
        int idx = i * 256 + tid;
        int r = idx >> 5, c4 = idx & 31;
        *(float4*)(&Ws[r][c4 * 4]) = *(const float4*)(W + (size_t)(colBase + r) * FD + c4 * 4);
    }
    __syncthreads();

    const int tx = tid & 15, ty = tid >> 4;
    const int r0 = ty * 2, r1 = ty * 2 + 1;
    float acc0[4] = {0.f, 0.f, 0.f, 0.f};
    float acc1[4] = {0.f, 0.f, 0.f, 0.f};
    for (int kk = 0; kk < FD; ++kk) {
        float a0 = Xs[r0][kk], a1 = Xs[r1][kk];
        float b0 = Ws[tx * 4 + 0][kk];
        float b1 = Ws[tx * 4 + 1][kk];
        float b2 = Ws[tx * 4 + 2][kk];
        float b3 = Ws[tx * 4 + 3][kk];
        acc0[0] += a0 * b0; acc0[1] += a0 * b1; acc0[2] += a0 * b2; acc0[3] += a0 * b3;
        acc1[0] += a1 * b0; acc1[1] += a1 * b1; acc1[2] += a1 * b2; acc1[3] += a1 * b3;
    }
    const int c = colBase + tx * 4;
    float4 bia = *(const float4*)(bias + c);
    float* dst = (c < FD) ? q32c : k32c;
    int cc = (c < FD) ? c : c - FD;
    size_t base = ((size_t)b * BN + rt * 32 + r0) * FD + cc;
    *(float4*)(dst + base)      = make_float4(acc0[0] + bia.x, acc0[1] + bia.y, acc0[2] + bia.z, acc0[3] + bia.w);
    *(float4*)(dst + base + FD) = make_float4(acc1[0] + bia.x, acc1[1] + bia.y, acc1[2] + bia.z, acc1[3] + bia.w);
}

// ---------------------------------------------------------------------------
// Kernel 2: fp32 softmax stats M,L for bt = b*24+23 only (y_last path).
// Column-chunked; also stores scaled scores s = e*SCALE to Sv (R14).
// ---------------------------------------------------------------------------
__global__ __launch_bounds__(256) void k_pass1(const float* __restrict__ q32c,
                                               const float* __restrict__ k32c,
                                               float* __restrict__ Sv,
                                               float* __restrict__ Mp,
                                               float* __restrict__ Lp) {
    __shared__ float Qs[32][129];
    __shared__ float Ks[64][129];
    const int tid = threadIdx.x;
    const int chunk = blockIdx.y;
    const int b = blockIdx.z;
    const int rowBase = blockIdx.x * 32;
    const float* qb = q32c + (size_t)b * BN * FD;
    const float* kb = k32c + (size_t)b * BN * FD;
    float* Sb = Sv + (size_t)b * BN * BN;

    for (int i = 0; i < 4; ++i) {
        int idx = i * 256 + tid;
        int r = idx >> 5, c4 = idx & 31;
        *(float4*)(&Qs[r][c4 * 4]) = *(const float4*)(qb + (size_t)(rowBase + r) * FD + c4 * 4);
    }
    const int tx = tid & 15, ty = tid >> 4;
    const int r0 = ty * 2, r1 = ty * 2 + 1;
    float m[2] = {-1e30f, -1e30f};
    float l[2] = {0.f, 0.f};

    for (int ct = chunk * 4; ct < chunk * 4 + 4; ++ct) {
        __syncthreads();
        for (int i = 0; i < 8; ++i) {
            int idx = i * 256 + tid;
            int r = idx >> 5, c4 = idx & 31;
            *(float4*)(&Ks[r][c4 * 4]) = *(const float4*)(kb + (size_t)(ct * 64 + r) * FD + c4 * 4);
        }
        __syncthreads();
        float e0[4] = {0.f, 0.f, 0.f, 0.f};
        float e1[4] = {0.f, 0.f, 0.f, 0.f};
        for (int kk = 0; kk < FD; ++kk) {
            float a0 = Qs[r0][kk], a1 = Qs[r1][kk];
            float b0 = Ks[tx * 4 + 0][kk];
            float b1 = Ks[tx * 4 + 1][kk];
            float b2 = Ks[tx * 4 + 2][kk];
            float b3 = Ks[tx * 4 + 3][kk];
            e0[0] += a0 * b0; e0[1] += a0 * b1; e0[2] += a0 * b2; e0[3] += a0 * b3;
            e1[0] += a1 * b0; e1[1] += a1 * b1; e1[2] += a1 * b2; e1[3] += a1 * b3;
        }
        // row r0
        {
            float s0 = e0[0] * SCALE, s1 = e0[1] * SCALE;
            float s2 = e0[2] * SCALE, s3 = e0[3] * SCALE;
            *(float4*)(Sb + (size_t)(rowBase + r0) * BN + ct * 64 + tx * 4) =
                make_float4(s0, s1, s2, s3);
            float tm = fmaxf(fmaxf(s0, s1), fmaxf(s2, s3));
            for (int s = 1; s < 16; s <<= 1) tm = fmaxf(tm, __shfl_xor(tm, s, 64));
            float ts = __expf(s0 - tm) + __expf(s1 - tm) + __expf(s2 - tm) + __expf(s3 - tm);
            for (int s = 1; s < 16; s <<= 1) ts += __shfl_xor(ts, s, 64);
            float mn = fmaxf(m[0], tm);
            l[0] = l[0] * __expf(m[0] - mn) + ts * __expf(tm - mn);
            m[0] = mn;
        }
        // row r1
        {
            float s0 = e1[0] * SCALE, s1 = e1[1] * SCALE;
            float s2 = e1[2] * SCALE, s3 = e1[3] * SCALE;
            *(float4*)(Sb + (size_t)(rowBase + r1) * BN + ct * 64 + tx * 4) =
                make_float4(s0, s1, s2, s3);
            float tm = fmaxf(fmaxf(s0, s1), fmaxf(s2, s3));
            for (int s = 1; s < 16; s <<= 1) tm = fmaxf(tm, __shfl_xor(tm, s, 64));
            float ts = __expf(s0 - tm) + __expf(s1 - tm) + __expf(s2 - tm) + __expf(s3 - tm);
            for (int s = 1; s < 16; s <<= 1) ts += __shfl_xor(ts, s, 64);
            float mn = fmaxf(m[1], tm);
            l[1] = l[1] * __expf(m[1] - mn) + ts * __expf(tm - mn);
            m[1] = mn;
        }
    }
    if (tx == 0) {
        size_t base = (size_t)chunk * BB * BN + (size_t)b * BN + rowBase;
        Mp[base + r0] = m[0];
        Lp[base + r0] = l[0];
        Mp[base + r1] = m[1];
        Lp[base + r1] = l[1];
    }
}

// ---------------------------------------------------------------------------
// Kernel 3 (lite): column sums from cached scores Sv, with the 4-chunk
// (m,l) merge INLINED (same chunk order as the removed k_mergeML ->
// bitwise identical Mv/Lv values).
// ---------------------------------------------------------------------------
__global__ __launch_bounds__(256) void k_colsum(const float* __restrict__ Sv,
                                                const float* __restrict__ Mp,
                                                const float* __restrict__ Lp,
                                                float* __restrict__ csp) {
    __shared__ float red[16][68];
    const int tid = threadIdx.x;
    const int rchunk = blockIdx.y;
    const int b = blockIdx.z;
    const int colBase = blockIdx.x * 64;
    const float* Sb = Sv + (size_t)b * BN * BN;
    const int tx = tid & 15, ty = tid >> 4;
    const int r0 = ty * 2, r1 = ty * 2 + 1;

    float acc[4] = {0.f, 0.f, 0.f, 0.f};
    for (int rt = rchunk * 4; rt < rchunk * 4 + 4; ++rt) {
        int n0 = rt * 32 + r0, n1 = rt * 32 + r1;
        float4 sA = *(const float4*)(Sb + (size_t)n0 * BN + colBase + tx * 4);
        float4 sB = *(const float4*)(Sb + (size_t)n1 * BN + colBase + tx * 4);
        // inline mergeML (chunk order 0..3, identical arithmetic)
        float m0 = -1e30f, l0 = 0.f, m1 = -1e30f, l1 = 0.f;
        for (int c = 0; c < 4; ++c) {
            size_t base = (size_t)c * BB * BN + (size_t)b * BN;
            float mc0 = Mp[base + n0], lc0 = Lp[base + n0];
            float mn0 = fmaxf(m0, mc0);
            l0 = l0 * __expf(m0 - mn0) + lc0 * __expf(mc0 - mn0);
            m0 = mn0;
            float mc1 = Mp[base + n1], lc1 = Lp[base + n1];
            float mn1 = fmaxf(m1, mc1);
            l1 = l1 * __expf(m1 - mn1) + lc1 * __expf(mc1 - mn1);
            m1 = mn1;
        }
        float il0 = 1.0f / l0, il1 = 1.0f / l1;
        acc[0] += __expf(sA.x - m0) * il0;
        acc[0] += __expf(sB.x - m1) * il1;
        acc[1] += __expf(sA.y - m0) * il0;
        acc[1] += __expf(sB.y - m1) * il1;
        acc[2] += __expf(sA.z - m0) * il0;
        acc[2] += __expf(sB.z - m1) * il1;
        acc[3] += __expf(sA.w - m0) * il0;
        acc[3] += __expf(sB.w - m1) * il1;
    }
    for (int j = 0; j < 4; ++j) red[ty][tx * 4 + j] = acc[j];
    __syncthreads();
    if (tid < 64) {
        float s = 0.f;
        for (int i = 0; i < 16; ++i) s += red[i][tid];
        csp[((size_t)rchunk * BB + b) * BN + colBase + tid] = s;
    }
}

// ---------------------------------------------------------------------------
// Kernel 4: index of 3rd-smallest column sum (top_k tie-break: lower index).
// ---------------------------------------------------------------------------
__global__ void k_top3(const float* __restrict__ csp, int* __restrict__ ylast) {
    __shared__ float sv[192];
    __shared__ int si[192];
    const int b = blockIdx.x;
    const int t = threadIdx.x;
    float bv[3] = {1e30f, 1e30f, 1e30f};
    int bi[3] = {0x7fffffff, 0x7fffffff, 0x7fffffff};
    for (int i = 0; i < 16; ++i) {
        int idx = t * 16 + i;
        float vv = 0.f;
        for (int c = 0; c < 8; ++c)
            vv += csp[((size_t)c * BB + b) * BN + idx];
        if (vv < bv[0]) {
            bv[2] = bv[1]; bi[2] = bi[1];
            bv[1] = bv[0]; bi[1] = bi[0];
            bv[0] = vv;    bi[0] = idx;
        } else if (vv < bv[1]) {
            bv[2] = bv[1]; bi[2] = bi[1];
            bv[1] = vv;    bi[1] = idx;
        } else if (vv < bv[2]) {
            bv[2] = vv;    bi[2] = idx;
        }
    }
    for (int j = 0; j < 3; ++j) { sv[t * 3 + j] = bv[j]; si[t * 3 + j] = bi[j]; }
    __syncthreads();
    if (t == 0) {
        float fv[3] = {1e30f, 1e30f, 1e30f};
        int fi[3] = {0x7fffffff, 0x7fffffff, 0x7fffffff};
        for (int c = 0; c < 192; ++c) {
            float vv = sv[c]; int ii = si[c];
            if (vv < fv[0] || (vv == fv[0] && ii < fi[0])) {
                fv[2] = fv[1]; fi[2] = fi[1];
                fv[1] = fv[0]; fi[1] = fi[0];
                fv[0] = vv;    fi[0] = ii;
            } else if (vv < fv[1] || (vv == fv[1] && ii < fi[1])) {
                fv[2] = fv[1]; fi[2] = fi[1];
                fv[1] = vv;    fi[1] = ii;
            } else if (vv < fv[2] || (vv == fv[2] && ii < fi[2])) {
                fv[2] = vv;    fi[2] = ii;
            }
        }
        ylast[b] = fi[2];
    }
}

// ---------------------------------------------------------------------------
// Kernel 5: mixup (round-1 exact FMA order; uint8-wrap cast).
// ---------------------------------------------------------------------------
__global__ void k_mixup(const float* __restrict__ x, const float* __restrict__ W,
                        const float* __restrict__ bias,
                        unsigned short* __restrict__ vtb,
                        const int* __restrict__ ylast) {
    const int b = blockIdx.y, t = blockIdx.x, f = threadIdx.x;
    const int y = ylast[b];
    const int ys = max(y - 1, 0), ye = min(y + 2, BN);
    const float* wrow = W + (size_t)(2 * FD + f) * FD;
    const float bia = bias[2 * FD + f];
    float s = 0.f;
    for (int r = ys; r < ye; ++r) {
        const float* xrow = x + ((size_t)(b * TT + t) * BN + r) * FD;
        float acc = 0.f;
        for (int kk = 0; kk < FD; ++kk) acc += xrow[kk] * wrow[kk];
        s += acc + bia;
    }
    s /= (float)(ye - ys);
    int ti = (int)s;                              // trunc toward zero
    unsigned u = ((unsigned)ti) & 0xFFu;          // wrap mod 256 (numpy/x86)
    vtb[((size_t)(b * TT + t) * FD + f) * BN + y] = f2bf((float)u);
}

// ---------------------------------------------------------------------------
// Kernel 6: flash attention core, SWAPPED-operand form, SHARED-fragment
// restructure: bk read once per (n4,t4) feeding both rg QK^T accumulators;
// both softmaxes write Ps2[wave][rg]; one PV loop with shared bv feeding
// both O[rg]. Per-accumulator MFMA order unchanged -> bitwise identical.
// LDS 52 KB (3 blocks/CU).
// ---------------------------------------------------------------------------
__global__ __launch_bounds__(256, 3) void k_flash(
    const unsigned short* __restrict__ qb, const unsigned short* __restrict__ kb,
    const unsigned short* __restrict__ vtb, float* __restrict__ vi)
{
    __shared__ __attribute__((aligned(16))) unsigned short Ks[64 * 136];
    __shared__ __attribute__((aligned(16))) unsigned short Vts[128 * 72];
    __shared__ __attribute__((aligned(16))) unsigned short Ps2[4][2][16 * 64];
    const int tid = threadIdx.x;
    // XCD swizzle: 768 blocks = 8 XCDs x 96; all 8 row-blocks of a bt share an XCD.
    const int f = blockIdx.y * 8 + blockIdx.x;
    const int s = (f & 7) * 96 + (f >> 3);
    const int bt = s >> 3;
    const int rowBase = (s & 7) * 128;
    const int lane = tid & 63, wave = tid >> 6;
    const int lx = lane & 15, quad = lane >> 4;
    const int swz = (lx & 7) << 3;               // Ps short-index XOR swizzle

    // Q fragments straight from global (read once, reused over all 16 ct).
    const unsigned short* qg = qb + ((size_t)bt * BN + rowBase) * FD;
    s8v aq[2][4];
    #pragma unroll
    for (int rg = 0; rg < 2; ++rg)
        #pragma unroll
        for (int t4 = 0; t4 < 4; ++t4)
            aq[rg][t4] = *(const s8v*)(qg + (size_t)(rg * 64 + wave * 16 + lx) * FD + t4 * 32 + quad * 8);

    f4v O[2][8];
    #pragma unroll
    for (int rg = 0; rg < 2; ++rg)
        for (int gg = 0; gg < 8; ++gg) O[rg][gg] = (f4v){0.f, 0.f, 0.f, 0.f};
    float mrow[2] = {-1e30f, -1e30f};
    float lrow[2] = {0.f, 0.f};

    const unsigned short* kgbase = kb + (size_t)bt * BN * FD;
    const unsigned short* vgbase = vtb + (size_t)bt * FD * BN;

    for (int ct = 0; ct < 16; ++ct) {
        __syncthreads();
        const unsigned short* kg = kgbase + (size_t)ct * 64 * FD;
        #pragma unroll
        for (int i = 0; i < 4; ++i) {
            int idx = i * 256 + tid, r = idx >> 4, c8 = idx & 15;
            *(int4*)(&Ks[r * 136 + c8 * 8]) = *(const int4*)(kg + r * FD + c8 * 8);
        }
        #pragma unroll
        for (int i = 0; i < 4; ++i) {
            int idx = i * 256 + tid, r = idx >> 3, c8 = idx & 7;
            *(int4*)(&Vts[r * 72 + c8 * 8]) = *(const int4*)(vgbase + (size_t)r * BN + ct * 64 + c8 * 8);
        }
        __syncthreads();

        // QK^T for BOTH row-groups with shared bk reads.
        f4v e2[2][4];
        #pragma unroll
        for (int n4 = 0; n4 < 4; ++n4) {
            s8v bk0 = *(const s8v*)(&Ks[(n4 * 16 + lx) * 136 + 0 * 32 + quad * 8]);
            s8v bk1 = *(const s8v*)(&Ks[(n4 * 16 + lx) * 136 + 1 * 32 + quad * 8]);
            s8v bk2 = *(const s8v*)(&Ks[(n4 * 16 + lx) * 136 + 2 * 32 + quad * 8]);
            s8v bk3 = *(const s8v*)(&Ks[(n4 * 16 + lx) * 136 + 3 * 32 + quad * 8]);
            #pragma unroll
            for (int rg = 0; rg < 2; ++rg) {
                f4v acc = (f4v){0.f, 0.f, 0.f, 0.f};
                acc = __builtin_amdgcn_mfma_f32_16x16x32_bf16(bk0, aq[rg][0], acc, 0, 0, 0);
                acc = __builtin_amdgcn_mfma_f32_16x16x32_bf16(bk1, aq[rg][1], acc, 0, 0, 0);
                acc = __builtin_amdgcn_mfma_f32_16x16x32_bf16(bk2, aq[rg][2], acc, 0, 0, 0);
                acc = __builtin_amdgcn_mfma_f32_16x16x32_bf16(bk3, aq[rg][3], acc, 0, 0, 0);
                #pragma unroll
                for (int r = 0; r < 4; ++r) acc[r] *= SCALE;
                e2[rg][n4] = acc;
            }
        }

        // Softmax per rg (identical arithmetic); P -> Ps2[wave][rg].
        #pragma unroll
        for (int rg = 0; rg < 2; ++rg) {
            float t0 = fmaxf(fmaxf(e2[rg][0][0], e2[rg][0][1]), fmaxf(e2[rg][0][2], e2[rg][0][3]));
            float t1 = fmaxf(fmaxf(e2[rg][1][0], e2[rg][1][1]), fmaxf(e2[rg][1][2], e2[rg][1][3]));
            float t2 = fmaxf(fmaxf(e2[rg][2][0], e2[rg][2][1]), fmaxf(e2[rg][2][2], e2[rg][2][3]));
            float t3 = fmaxf(fmaxf(e2[rg][3][0], e2[rg][3][1]), fmaxf(e2[rg][3][2], e2[rg][3][3]));
            float tm = fmaxf(fmaxf(t0, t1), fmaxf(t2, t3));
            tm = fmaxf(tm, __shfl_xor(tm, 16, 64));
            tm = fmaxf(tm, __shfl_xor(tm, 32, 64));
            float mo = mrow[rg];
            float mn = fmaxf(mo, tm);
            mrow[rg] = mn;
            float ps0 = 0.f, ps1 = 0.f, ps2 = 0.f, ps3 = 0.f;
            #pragma unroll
            for (int n4 = 0; n4 < 4; ++n4) {
                float p0 = __expf(e2[rg][n4][0] - mn);
                float p1 = __expf(e2[rg][n4][1] - mn);
                float p2 = __expf(e2[rg][n4][2] - mn);
                float p3 = __expf(e2[rg][n4][3] - mn);
                e2[rg][n4][0] = p0; e2[rg][n4][1] = p1; e2[rg][n4][2] = p2; e2[rg][n4][3] = p3;
                ps0 += p0; ps1 += p1; ps2 += p2; ps3 += p3;
            }
            float ps = (ps0 + ps1) + (ps2 + ps3);
            ps += __shfl_xor(ps, 16, 64);
            ps += __shfl_xor(ps, 32, 64);
            if (tm > mo) {                     // exact: alpha==1 when not taken
                float alpha = __expf(mo - mn);
                lrow[rg] = lrow[rg] * alpha + ps;
                #pragma unroll
                for (int gg = 0; gg < 8; ++gg)
                    for (int r = 0; r < 4; ++r) O[rg][gg][r] *= alpha;
            } else {
                lrow[rg] += ps;
            }
            #pragma unroll
            for (int n4 = 0; n4 < 4; ++n4) {
                unsigned w0 = (unsigned)f2bf(e2[rg][n4][0]) | ((unsigned)f2bf(e2[rg][n4][1]) << 16);
                unsigned w1 = (unsigned)f2bf(e2[rg][n4][2]) | ((unsigned)f2bf(e2[rg][n4][3]) << 16);
                int col = (n4 * 16 + quad * 4) ^ swz;
                uint2 w = {w0, w1};
                *(uint2*)(&Ps2[wave][rg][lx * 64 + col]) = w;
            }
        }

        // PV for both rg with shared bv reads.
        #pragma unroll
        for (int k2 = 0; k2 < 2; ++k2) {
            s8v bp0 = *(const s8v*)(&Ps2[wave][0][lx * 64 + ((k2 * 32 + quad * 8) ^ swz)]);
            s8v bp1 = *(const s8v*)(&Ps2[wave][1][lx * 64 + ((k2 * 32 + quad * 8) ^ swz)]);
            #pragma unroll
            for (int gg = 0; gg < 8; ++gg) {
                s8v bv = *(const s8v*)(&Vts[(gg * 16 + lx) * 72 + k2 * 32 + quad * 8]);
                O[0][gg] = __builtin_amdgcn_mfma_f32_16x16x32_bf16(bv, bp0, O[0][gg], 0, 0, 0);
                O[1][gg] = __builtin_amdgcn_mfma_f32_16x16x32_bf16(bv, bp1, O[1][gg], 0, 0, 0);
            }
        }
    }
    #pragma unroll
    for (int rg = 0; rg < 2; ++rg) {
        const int qglob = rowBase + rg * 64 + wave * 16 + lx;
        float inv = 1.0f / lrow[rg];
        float* vrow = vi + ((size_t)bt * BN + qglob) * FD;
        #pragma unroll
        for (int gg = 0; gg < 8; ++gg) {
            float4 o4 = make_float4(O[rg][gg][0] * inv, O[rg][gg][1] * inv,
                                    O[rg][gg][2] * inv, O[rg][gg][3] * inv);
            *(float4*)(vrow + gg * 16 + quad * 4) = o4;
        }
    }
}

// ---------------------------------------------------------------------------
// Kernel 7: FF1+gelu+FF2+residual+LayerNorm. Scalar fp32, R12-validated
// (bitwise-exact; at its LDS-issue structural floor).
// ---------------------------------------------------------------------------
__global__ __launch_bounds__(256) void k_ffn(const float* __restrict__ vi,
                                             const float* __restrict__ x,
                                             const float* __restrict__ W1,
                                             const float* __restrict__ b1,
                                             const float* __restrict__ W2,
                                             const float* __restrict__ b2,
                                             const float* __restrict__ g,
                                             const float* __restrict__ lb,
                                             float* __restrict__ out) {
    __shared__ float Qs[64][132];
    __shared__ float KVs[32][132];
    const int tid = threadIdx.x;
    const int bt = blockIdx.y;
    const int rowBase = blockIdx.x * 64;
    const int tx = tid & 15, ty = tid >> 4;       // ty 0..15
    const int r0 = ty * 4;                        // 4 rows per thread

    const float* vb = vi + ((size_t)bt * BN + rowBase) * FD;
    for (int i = 0; i < 8; ++i) {
        int idx = i * 256 + tid;
        int r = idx >> 5, c4 = idx & 31;
        *(float4*)(&Qs[r][c4 * 4]) = *(const float4*)(vb + (size_t)r * FD + c4 * 4);
    }

    float h[4][8];
    {
        float t[4][8] = {};
        #pragma unroll
        for (int ch = 0; ch < 4; ++ch) {
            __syncthreads();
            for (int i = 0; i < 4; ++i) {
                int idx = i * 256 + tid;
                int r = idx >> 5, c4 = idx & 31;
                *(float4*)(&KVs[r][c4 * 4]) = *(const float4*)(W1 + (size_t)(ch * 32 + r) * FD + c4 * 4);
            }
            __syncthreads();
            for (int kk = 0; kk < FD; ++kk) {
                float a0 = Qs[r0 + 0][kk], a1 = Qs[r0 + 1][kk];
                float a2 = Qs[r0 + 2][kk], a3 = Qs[r0 + 3][kk];
                #pragma unroll
                for (int jj = 0; jj < 2; ++jj) {
                    int j = jj + 2 * ch;      // f = tx + 16*j = ch*32 + jj*16 + tx
                    float w = KVs[tx + 16 * jj][kk];
                    t[0][j] += a0 * w;
                    t[1][j] += a1 * w;
                    t[2][j] += a2 * w;
                    t[3][j] += a3 * w;
                }
            }
        }
        #pragma unroll
        for (int j = 0; j < 8; ++j) {
            int f = tx + 16 * j;
            float bj = b1[f];
            #pragma unroll
            for (int rr = 0; rr < 4; ++rr) {
                float z = t[rr][j] + bj;
                h[rr][j] = 0.5f * z * (1.0f + erff(z * GELU_K));
            }
        }
    }
    __syncthreads();
    #pragma unroll
    for (int j = 0; j < 8; ++j)
        #pragma unroll
        for (int rr = 0; rr < 4; ++rr)
            Qs[r0 + rr][tx + 16 * j] = h[rr][j];
    __syncthreads();

    float z[4][8];
    {
        float t[4][8] = {};
        #pragma unroll
        for (int ch = 0; ch < 4; ++ch) {
            __syncthreads();
            for (int i = 0; i < 4; ++i) {
                int idx = i * 256 + tid;
                int r = idx >> 5, c4 = idx & 31;
                *(float4*)(&KVs[r][c4 * 4]) = *(const float4*)(W2 + (size_t)(ch * 32 + r) * FD + c4 * 4);
            }
            __syncthreads();
            for (int kk = 0; kk < FD; ++kk) {
                float a0 = Qs[r0 + 0][kk], a1 = Qs[r0 + 1][kk];
                float a2 = Qs[r0 + 2][kk], a3 = Qs[r0 + 3][kk];
                #pragma unroll
                for (int jj = 0; jj < 2; ++jj) {
                    int j = jj + 2 * ch;
                    float w = KVs[tx + 16 * jj][kk];
                    t[0][j] += a0 * w;
                    t[1][j] += a1 * w;
                    t[2][j] += a2 * w;
                    t[3][j] += a3 * w;
                }
            }
        }
        #pragma unroll
        for (int j = 0; j < 8; ++j) {
            int f = tx + 16 * j;
            float bj = b2[f];
            #pragma unroll
            for (int rr = 0; rr < 4; ++rr) z[rr][j] = t[rr][j] + bj;
        }
    }

    const float* xb = x + ((size_t)bt * BN + rowBase) * FD;
    float res[4][8];
    float sum[4] = {0.f, 0.f, 0.f, 0.f};
    #pragma unroll
    for (int j = 0; j < 8; ++j) {
        int f = tx + 16 * j;
        #pragma unroll
        for (int rr = 0; rr < 4; ++rr) {
            float v = z[rr][j] + xb[(size_t)(r0 + rr) * FD + f];
            res[rr][j] = v;
            sum[rr] += v;
        }
    }
    #pragma unroll
    for (int rr = 0; rr < 4; ++rr)
        for (int s = 1; s < 16; s <<= 1) sum[rr] += __shfl_xor(sum[rr], s, 64);
    float mu[4], q[4] = {0.f, 0.f, 0.f, 0.f};
    #pragma unroll
    for (int rr = 0; rr < 4; ++rr) mu[rr] = sum[rr] * (1.0f / FD);
    #pragma unroll
    for (int j = 0; j < 8; ++j)
        #pragma unroll
        for (int rr = 0; rr < 4; ++rr) {
            float d = res[rr][j] - mu[rr];
            q[rr] += d * d;
        }
    #pragma unroll
    for (int rr = 0; rr < 4; ++rr)
        for (int s = 1; s < 16; s <<= 1) q[rr] += __shfl_xor(q[rr], s, 64);
    float rs[4];
    #pragma unroll
    for (int rr = 0; rr < 4; ++rr) rs[rr] = rsqrtf(q[rr] * (1.0f / FD) + 1e-5f);
    float* ob = out + ((size_t)bt * BN + rowBase) * FD;
    #pragma unroll
    for (int j = 0; j < 8; ++j) {
        int f = tx + 16 * j;
        float gf = g[f], bf = lb[f];
        #pragma unroll
        for (int rr = 0; rr < 4; ++rr)
            ob[(size_t)(r0 + rr) * FD + f] = (res[rr][j] - mu[rr]) * rs[rr] * gf + bf;
    }
}

// ---------------------------------------------------------------------------
extern "C" void kernel_launch(void* const* d_in, const int* in_sizes, int n_in,
                              void* d_out, int out_size, void* d_ws, size_t ws_size,
                              hipStream_t stream) {
    const float* x     = (const float*)d_in[0];
    const float* W_xff = (const float*)d_in[1];
    const float* b_xff = (const float*)d_in[2];
    const float* W_ff1 = (const float*)d_in[3];
    const float* b_ff1 = (const float*)d_in[4];
    const float* W_ff2 = (const float*)d_in[5];
    const float* b_ff2 = (const float*)d_in[6];
    const float* ln_g  = (const float*)d_in[7];
    const float* ln_b  = (const float*)d_in[8];
    float* out = (float*)d_out;

    char* w = (char*)d_ws;
    unsigned short* qb16 = (unsigned short*)w;  w += (size_t)BTN * FD * 2;
    unsigned short* kb16 = (unsigned short*)w;  w += (size_t)BTN * FD * 2;
    unsigned short* vtb  = (unsigned short*)w;  w += (size_t)BTN * FD * 2;
    unsigned short* wxb  = (unsigned short*)w;  w += (size_t)3 * FD * FD * 2;
    // vi aliases the region holding Sv/q32c/k32c/stats: all consumed before
    // k_flash writes vi (stream-ordered). Sv (16.8 MB) lives in the former
    // xb slot (25.2 MB) at the start of the alias region.
    char* alias = w;
    float* vi = (float*)alias;                  // BTN*FD*4 = 50.3 MB
    float* Sv = (float*)alias;                  // BB*BN*BN*4 = 16.8 MB (pre-flash)
    alias += (size_t)BTN * FD * 2;              // (former xb slot)
    float* q32c = (float*)alias;                alias += (size_t)BB * BN * FD * 4;
    float* k32c = (float*)alias;                alias += (size_t)BB * BN * FD * 4;
    float* Mv   = (float*)alias;                alias += (size_t)BB * BN * 4;
    float* Lv   = (float*)alias;                alias += (size_t)BB * BN * 4;
    int* ylast  = (int*)alias;                  alias += 256;   // padded
    float* Mp   = (float*)alias;                alias += (size_t)4 * BB * BN * 4;
    float* Lp   = (float*)alias;                alias += (size_t)4 * BB * BN * 4;
    float* csp  = (float*)alias;                alias += (size_t)8 * BB * BN * 4;
    (void)Mv; (void)Lv;

    k_convw    <<<dim3(192),             256, 0, stream>>>(W_xff, wxb, 3 * FD * FD);
    k_qkv_mfma <<<dim3(BTN / 64),        256, 0, stream>>>(x, wxb, b_xff, qb16, kb16, vtb);
    k_qkv32    <<<dim3(BB * 32, 4),      256, 0, stream>>>(x, W_xff, b_xff, q32c, k32c);
    k_pass1    <<<dim3(32, 4, BB),       256, 0, stream>>>(q32c, k32c, Sv, Mp, Lp);
    k_colsum   <<<dim3(16, 8, BB),       256, 0, stream>>>(Sv, Mp, Lp, csp);
    k_top3     <<<dim3(BB),               64, 0, stream>>>(csp, ylast);
    k_mixup    <<<dim3(FRONT_T, BB),     128, 0, stream>>>(x, W_xff, b_xff, vtb, ylast);
    k_flash    <<<dim3(8, BT),           256, 0, stream>>>(qb16, kb16, vtb, vi);
    k_ffn      <<<dim3(16, BT),          256, 0, stream>>>(vi, x, W_ff1, b_ff1, W_ff2, b_ff2,
                                                           ln_g, ln_b, out);
}

// Round 17
// 438.550 us; speedup vs baseline: 1.2277x; 1.2277x over previous
//
#include <hip/hip_runtime.h>
#include <math.h>

#define BB 4
#define TT 24
#define BN 1024
#define FD 128
#define BT (BB*TT)
#define BTN (BT*BN)
#define FRONT_T 12
#define SCALE 0.08838834764831845f   // 1/sqrt(128)
#define GELU_K 0.7071067811865476f   // 1/sqrt(2)

typedef __attribute__((ext_vector_type(8))) short s8v;   // 8 bf16 (4 VGPRs)
typedef __attribute__((ext_vector_type(4))) float f4v;   // 4 fp32 acc

static __device__ __forceinline__ unsigned short f2bf(float f) {
    union { float f; unsigned u; } c; c.f = f;
    unsigned u = c.u + 0x7FFFu + ((c.u >> 16) & 1u);   // RNE
    return (unsigned short)(u >> 16);
}

// ---------------------------------------------------------------------------
// W_xff -> bf16.
// ---------------------------------------------------------------------------
__global__ void k_convw(const float* __restrict__ W, unsigned short* __restrict__ wb, int n) {
    int i = blockIdx.x * 256 + threadIdx.x;
    if (i < n) wb[i] = f2bf(W[i]);
}

// ---------------------------------------------------------------------------
// Bulk qkv GEMM in bf16 MFMA. 64-row block computes ALL 6 col-tiles; x is
// staged+converted once per block (validated R13).
// ---------------------------------------------------------------------------
__global__ __launch_bounds__(256, 3) void k_qkv_mfma(
    const float* __restrict__ x, const unsigned short* __restrict__ wb,
    const float* __restrict__ bias,
    unsigned short* __restrict__ qb16, unsigned short* __restrict__ kb16,
    unsigned short* __restrict__ vtb)
{
    __shared__ __attribute__((aligned(16))) unsigned short Xs[64 * 136];
    __shared__ __attribute__((aligned(16))) unsigned short Ws[64 * 136];
    __shared__ __attribute__((aligned(16))) unsigned short Cs[64 * 72];
    const int tid = threadIdx.x;
    const int rowBase = blockIdx.x * 64;
    const int lane = tid & 63, wave = tid >> 6;
    const int lx = lane & 15, quad = lane >> 4;

    // stage Xs once: fp32 -> bf16 (same f2bf as the removed k_convx)
    for (int i = 0; i < 4; ++i) {
        int idx = i * 256 + tid, r = idx >> 4, c8 = idx & 15;
        const float* src = x + (size_t)(rowBase + r) * FD + c8 * 8;
        float4 u0 = *(const float4*)(src);
        float4 u1 = *(const float4*)(src + 4);
        ushort4 h0 = {f2bf(u0.x), f2bf(u0.y), f2bf(u0.z), f2bf(u0.w)};
        ushort4 h1 = {f2bf(u1.x), f2bf(u1.y), f2bf(u1.z), f2bf(u1.w)};
        *(ushort4*)(&Xs[r * 136 + c8 * 8])     = h0;
        *(ushort4*)(&Xs[r * 136 + c8 * 8 + 4]) = h1;
    }

    for (int cb = 0; cb < 6; ++cb) {
        __syncthreads();                     // Xs ready / prev Ws,Cs consumed
        const int colBase = cb * 64;
        for (int i = 0; i < 4; ++i) {
            int idx = i * 256 + tid, r = idx >> 4, c8 = idx & 15;
            *(int4*)(&Ws[r * 136 + c8 * 8]) = *(const int4*)(wb + (size_t)(colBase + r) * FD + c8 * 8);
        }
        __syncthreads();

        f4v acc[4];
        for (int gg = 0; gg < 4; ++gg) acc[gg] = (f4v){0.f, 0.f, 0.f, 0.f};
        for (int t4 = 0; t4 < 4; ++t4) {
            s8v a = *(const s8v*)(&Xs[(wave * 16 + lx) * 136 + t4 * 32 + quad * 8]);
            for (int gg = 0; gg < 4; ++gg) {
                s8v b = *(const s8v*)(&Ws[(gg * 16 + lx) * 136 + t4 * 32 + quad * 8]);
                acc[gg] = __builtin_amdgcn_mfma_f32_16x16x32_bf16(a, b, acc[gg], 0, 0, 0);
            }
        }

        const int n0 = wave * 16 + quad * 4;          // C rows (n_local)
        if (colBase < 2 * FD) {
            for (int gg = 0; gg < 4; ++gg) {
                float bb = bias[colBase + gg * 16 + lx];
                for (int r = 0; r < 4; ++r)
                    Cs[(n0 + r) * 72 + gg * 16 + lx] = f2bf(acc[gg][r] + bb);
            }
            __syncthreads();
            unsigned short* dst = (colBase < FD) ? qb16 : kb16;
            const int cc0 = colBase & (FD - 1);
            for (int i = 0; i < 2; ++i) {
                int idx = i * 256 + tid, r = idx >> 3, c8 = idx & 7;
                *(int4*)(dst + (size_t)(rowBase + r) * FD + cc0 + c8 * 8) =
                    *(const int4*)(&Cs[r * 72 + c8 * 8]);
            }
        } else {
            for (int gg = 0; gg < 4; ++gg) {
                float bb = bias[colBase + gg * 16 + lx];
                for (int r = 0; r < 4; ++r)
                    Cs[(gg * 16 + lx) * 72 + n0 + r] = f2bf(acc[gg][r] + bb);
            }
            __syncthreads();
            const int bt = rowBase >> 10, nBase = rowBase & 1023, cc0 = colBase - 2 * FD;
            for (int i = 0; i < 2; ++i) {
                int idx = i * 256 + tid, f = idx >> 3, c8 = idx & 7;
                *(int4*)(vtb + ((size_t)bt * FD + cc0 + f) * BN + nBase + c8 * 8) =
                    *(const int4*)(&Cs[f * 72 + c8 * 8]);
            }
        }
    }
}

// ---------------------------------------------------------------------------
// Exact fp32 GEMM (round-1 verbatim arithmetic) for the bt%24==23 slices
// only -> q32c/k32c bitwise identical to the round-1/4 y_last path.
// ---------------------------------------------------------------------------
__global__ __launch_bounds__(256) void k_qkv32(const float* __restrict__ x,
                                               const float* __restrict__ W,
                                               const float* __restrict__ bias,
                                               float* __restrict__ q32c,
                                               float* __restrict__ k32c) {
    __shared__ float Xs[32][129];
    __shared__ float Ws[64][129];
    const int tid = threadIdx.x;
    const int b = blockIdx.x >> 5;
    const int rt = blockIdx.x & 31;
    const int xrow0 = (b * TT + (TT - 1)) * BN + rt * 32;
    const int colBase = blockIdx.y * 64;      // 0..192 (q,k cols only)

    for (int i = 0; i < 4; ++i) {
        int idx = i * 256 + tid;
        int r = idx >> 5, c4 = idx & 31;
        *(float4*)(&Xs[r][c4 * 4]) = *(const float4*)(x + (size_t)(xrow0 + r) * FD + c4 * 4);
    }
    for (int i = 0; i < 8; ++i) {
        int idx = i * 256 + tid;
        int r = idx >> 5, c4 = idx & 31;
        *(float4*)(&Ws[r][c4 * 4]) = *(const float4*)(W + (size_t)(colBase + r) * FD + c4 * 4);
    }
    __syncthreads();

    const int tx = tid & 15, ty = tid >> 4;
    const int r0 = ty * 2, r1 = ty * 2 + 1;
    float acc0[4] = {0.f, 0.f, 0.f, 0.f};
    float acc1[4] = {0.f, 0.f, 0.f, 0.f};
    for (int kk = 0; kk < FD; ++kk) {
        float a0 = Xs[r0][kk], a1 = Xs[r1][kk];
        float b0 = Ws[tx * 4 + 0][kk];
        float b1 = Ws[tx * 4 + 1][kk];
        float b2 = Ws[tx * 4 + 2][kk];
        float b3 = Ws[tx * 4 + 3][kk];
        acc0[0] += a0 * b0; acc0[1] += a0 * b1; acc0[2] += a0 * b2; acc0[3] += a0 * b3;
        acc1[0] += a1 * b0; acc1[1] += a1 * b1; acc1[2] += a1 * b2; acc1[3] += a1 * b3;
    }
    const int c = colBase + tx * 4;
    float4 bia = *(const float4*)(bias + c);
    float* dst = (c < FD) ? q32c : k32c;
    int cc = (c < FD) ? c : c - FD;
    size_t base = ((size_t)b * BN + rt * 32 + r0) * FD + cc;
    *(float4*)(dst + base)      = make_float4(acc0[0] + bia.x, acc0[1] + bia.y, acc0[2] + bia.z, acc0[3] + bia.w);
    *(float4*)(dst + base + FD) = make_float4(acc1[0] + bia.x, acc1[1] + bia.y, acc1[2] + bia.z, acc1[3] + bia.w);
}

// ---------------------------------------------------------------------------
// Kernel 2: fp32 softmax stats M,L for bt = b*24+23 only (y_last path).
// Column-chunked; also stores scaled scores s = e*SCALE to Sv (R14).
// ---------------------------------------------------------------------------
__global__ __launch_bounds__(256) void k_pass1(const float* __restrict__ q32c,
                                               const float* __restrict__ k32c,
                                               float* __restrict__ Sv,
                                               float* __restrict__ Mp,
                                               float* __restrict__ Lp) {
    __shared__ float Qs[32][129];
    __shared__ float Ks[64][129];
    const int tid = threadIdx.x;
    const int chunk = blockIdx.y;
    const int b = blockIdx.z;
    const int rowBase = blockIdx.x * 32;
    const float* qb = q32c + (size_t)b * BN * FD;
    const float* kb = k32c + (size_t)b * BN * FD;
    float* Sb = Sv + (size_t)b * BN * BN;

    for (int i = 0; i < 4; ++i) {
        int idx = i * 256 + tid;
        int r = idx >> 5, c4 = idx & 31;
        *(float4*)(&Qs[r][c4 * 4]) = *(const float4*)(qb + (size_t)(rowBase + r) * FD + c4 * 4);
    }
    const int tx = tid & 15, ty = tid >> 4;
    const int r0 = ty * 2, r1 = ty * 2 + 1;
    float m[2] = {-1e30f, -1e30f};
    float l[2] = {0.f, 0.f};

    for (int ct = chunk * 4; ct < chunk * 4 + 4; ++ct) {
        __syncthreads();
        for (int i = 0; i < 8; ++i) {
            int idx = i * 256 + tid;
            int r = idx >> 5, c4 = idx & 31;
            *(float4*)(&Ks[r][c4 * 4]) = *(const float4*)(kb + (size_t)(ct * 64 + r) * FD + c4 * 4);
        }
        __syncthreads();
        float e0[4] = {0.f, 0.f, 0.f, 0.f};
        float e1[4] = {0.f, 0.f, 0.f, 0.f};
        for (int kk = 0; kk < FD; ++kk) {
            float a0 = Qs[r0][kk], a1 = Qs[r1][kk];
            float b0 = Ks[tx * 4 + 0][kk];
            float b1 = Ks[tx * 4 + 1][kk];
            float b2 = Ks[tx * 4 + 2][kk];
            float b3 = Ks[tx * 4 + 3][kk];
            e0[0] += a0 * b0; e0[1] += a0 * b1; e0[2] += a0 * b2; e0[3] += a0 * b3;
            e1[0] += a1 * b0; e1[1] += a1 * b1; e1[2] += a1 * b2; e1[3] += a1 * b3;
        }
        // row r0
        {
            float s0 = e0[0] * SCALE, s1 = e0[1] * SCALE;
            float s2 = e0[2] * SCALE, s3 = e0[3] * SCALE;
            *(float4*)(Sb + (size_t)(rowBase + r0) * BN + ct * 64 + tx * 4) =
                make_float4(s0, s1, s2, s3);
            float tm = fmaxf(fmaxf(s0, s1), fmaxf(s2, s3));
            for (int s = 1; s < 16; s <<= 1) tm = fmaxf(tm, __shfl_xor(tm, s, 64));
            float ts = __expf(s0 - tm) + __expf(s1 - tm) + __expf(s2 - tm) + __expf(s3 - tm);
            for (int s = 1; s < 16; s <<= 1) ts += __shfl_xor(ts, s, 64);
            float mn = fmaxf(m[0], tm);
            l[0] = l[0] * __expf(m[0] - mn) + ts * __expf(tm - mn);
            m[0] = mn;
        }
        // row r1
        {
            float s0 = e1[0] * SCALE, s1 = e1[1] * SCALE;
            float s2 = e1[2] * SCALE, s3 = e1[3] * SCALE;
            *(float4*)(Sb + (size_t)(rowBase + r1) * BN + ct * 64 + tx * 4) =
                make_float4(s0, s1, s2, s3);
            float tm = fmaxf(fmaxf(s0, s1), fmaxf(s2, s3));
            for (int s = 1; s < 16; s <<= 1) tm = fmaxf(tm, __shfl_xor(tm, s, 64));
            float ts = __expf(s0 - tm) + __expf(s1 - tm) + __expf(s2 - tm) + __expf(s3 - tm);
            for (int s = 1; s < 16; s <<= 1) ts += __shfl_xor(ts, s, 64);
            float mn = fmaxf(m[1], tm);
            l[1] = l[1] * __expf(m[1] - mn) + ts * __expf(tm - mn);
            m[1] = mn;
        }
    }
    if (tx == 0) {
        size_t base = (size_t)chunk * BB * BN + (size_t)b * BN + rowBase;
        Mp[base + r0] = m[0];
        Lp[base + r0] = l[0];
        Mp[base + r1] = m[1];
        Lp[base + r1] = l[1];
    }
}

// ---------------------------------------------------------------------------
// Kernel 3 (lite): column sums from cached scores Sv, with the 4-chunk
// (m,l) merge INLINED (same chunk order as the removed k_mergeML ->
// bitwise identical values). Validated R15.
// ---------------------------------------------------------------------------
__global__ __launch_bounds__(256) void k_colsum(const float* __restrict__ Sv,
                                                const float* __restrict__ Mp,
                                                const float* __restrict__ Lp,
                                                float* __restrict__ csp) {
    __shared__ float red[16][68];
    const int tid = threadIdx.x;
    const int rchunk = blockIdx.y;
    const int b = blockIdx.z;
    const int colBase = blockIdx.x * 64;
    const float* Sb = Sv + (size_t)b * BN * BN;
    const int tx = tid & 15, ty = tid >> 4;
    const int r0 = ty * 2, r1 = ty * 2 + 1;

    float acc[4] = {0.f, 0.f, 0.f, 0.f};
    for (int rt = rchunk * 4; rt < rchunk * 4 + 4; ++rt) {
        int n0 = rt * 32 + r0, n1 = rt * 32 + r1;
        float4 sA = *(const float4*)(Sb + (size_t)n0 * BN + colBase + tx * 4);
        float4 sB = *(const float4*)(Sb + (size_t)n1 * BN + colBase + tx * 4);
        // inline mergeML (chunk order 0..3, identical arithmetic)
        float m0 = -1e30f, l0 = 0.f, m1 = -1e30f, l1 = 0.f;
        for (int c = 0; c < 4; ++c) {
            size_t base = (size_t)c * BB * BN + (size_t)b * BN;
            float mc0 = Mp[base + n0], lc0 = Lp[base + n0];
            float mn0 = fmaxf(m0, mc0);
            l0 = l0 * __expf(m0 - mn0) + lc0 * __expf(mc0 - mn0);
            m0 = mn0;
            float mc1 = Mp[base + n1], lc1 = Lp[base + n1];
            float mn1 = fmaxf(m1, mc1);
            l1 = l1 * __expf(m1 - mn1) + lc1 * __expf(mc1 - mn1);
            m1 = mn1;
        }
        float il0 = 1.0f / l0, il1 = 1.0f / l1;
        acc[0] += __expf(sA.x - m0) * il0;
        acc[0] += __expf(sB.x - m1) * il1;
        acc[1] += __expf(sA.y - m0) * il0;
        acc[1] += __expf(sB.y - m1) * il1;
        acc[2] += __expf(sA.z - m0) * il0;
        acc[2] += __expf(sB.z - m1) * il1;
        acc[3] += __expf(sA.w - m0) * il0;
        acc[3] += __expf(sB.w - m1) * il1;
    }
    for (int j = 0; j < 4; ++j) red[ty][tx * 4 + j] = acc[j];
    __syncthreads();
    if (tid < 64) {
        float s = 0.f;
        for (int i = 0; i < 16; ++i) s += red[i][tid];
        csp[((size_t)rchunk * BB + b) * BN + colBase + tid] = s;
    }
}

// ---------------------------------------------------------------------------
// Kernel 4: index of 3rd-smallest column sum (top_k tie-break: lower index).
// ---------------------------------------------------------------------------
__global__ void k_top3(const float* __restrict__ csp, int* __restrict__ ylast) {
    __shared__ float sv[192];
    __shared__ int si[192];
    const int b = blockIdx.x;
    const int t = threadIdx.x;
    float bv[3] = {1e30f, 1e30f, 1e30f};
    int bi[3] = {0x7fffffff, 0x7fffffff, 0x7fffffff};
    for (int i = 0; i < 16; ++i) {
        int idx = t * 16 + i;
        float vv = 0.f;
        for (int c = 0; c < 8; ++c)
            vv += csp[((size_t)c * BB + b) * BN + idx];
        if (vv < bv[0]) {
            bv[2] = bv[1]; bi[2] = bi[1];
            bv[1] = bv[0]; bi[1] = bi[0];
            bv[0] = vv;    bi[0] = idx;
        } else if (vv < bv[1]) {
            bv[2] = bv[1]; bi[2] = bi[1];
            bv[1] = vv;    bi[1] = idx;
        } else if (vv < bv[2]) {
            bv[2] = vv;    bi[2] = idx;
        }
    }
    for (int j = 0; j < 3; ++j) { sv[t * 3 + j] = bv[j]; si[t * 3 + j] = bi[j]; }
    __syncthreads();
    if (t == 0) {
        float fv[3] = {1e30f, 1e30f, 1e30f};
        int fi[3] = {0x7fffffff, 0x7fffffff, 0x7fffffff};
        for (int c = 0; c < 192; ++c) {
            float vv = sv[c]; int ii = si[c];
            if (vv < fv[0] || (vv == fv[0] && ii < fi[0])) {
                fv[2] = fv[1]; fi[2] = fi[1];
                fv[1] = fv[0]; fi[1] = fi[0];
                fv[0] = vv;    fi[0] = ii;
            } else if (vv < fv[1] || (vv == fv[1] && ii < fi[1])) {
                fv[2] = fv[1]; fi[2] = fi[1];
                fv[1] = vv;    fi[1] = ii;
            } else if (vv < fv[2] || (vv == fv[2] && ii < fi[2])) {
                fv[2] = vv;    fi[2] = ii;
            }
        }
        ylast[b] = fi[2];
    }
}

// ---------------------------------------------------------------------------
// Kernel 5: mixup (round-1 exact FMA order; uint8-wrap cast).
// ---------------------------------------------------------------------------
__global__ void k_mixup(const float* __restrict__ x, const float* __restrict__ W,
                        const float* __restrict__ bias,
                        unsigned short* __restrict__ vtb,
                        const int* __restrict__ ylast) {
    const int b = blockIdx.y, t = blockIdx.x, f = threadIdx.x;
    const int y = ylast[b];
    const int ys = max(y - 1, 0), ye = min(y + 2, BN);
    const float* wrow = W + (size_t)(2 * FD + f) * FD;
    const float bia = bias[2 * FD + f];
    float s = 0.f;
    for (int r = ys; r < ye; ++r) {
        const float* xrow = x + ((size_t)(b * TT + t) * BN + r) * FD;
        float acc = 0.f;
        for (int kk = 0; kk < FD; ++kk) acc += xrow[kk] * wrow[kk];
        s += acc + bia;
    }
    s /= (float)(ye - ys);
    int ti = (int)s;                              // trunc toward zero
    unsigned u = ((unsigned)ti) & 0xFFu;          // wrap mod 256 (numpy/x86)
    vtb[((size_t)(b * TT + t) * FD + f) * BN + y] = f2bf((float)u);
}

// ---------------------------------------------------------------------------
// Kernel 6: flash attention core, SWAPPED-operand form — EXACT R4/R14
// validated structure (per-rg loop; R15's shared-fragment variant spilled
// e2[] to scratch: FETCH 51->368 MB, 228 us — reverted, rule reaffirmed:
// no added persistent register state across the softmax region).
// ---------------------------------------------------------------------------
__global__ __launch_bounds__(256, 3) void k_flash(
    const unsigned short* __restrict__ qb, const unsigned short* __restrict__ kb,
    const unsigned short* __restrict__ vtb, float* __restrict__ vi)
{
    __shared__ __attribute__((aligned(16))) unsigned short Ks[64 * 136];
    __shared__ __attribute__((aligned(16))) unsigned short Vts[128 * 72];
    __shared__ __attribute__((aligned(16))) unsigned short Ps[4][16 * 64];
    const int tid = threadIdx.x;
    // XCD swizzle: 768 blocks = 8 XCDs x 96; all 8 row-blocks of a bt share an XCD.
    const int f = blockIdx.y * 8 + blockIdx.x;
    const int s = (f & 7) * 96 + (f >> 3);
    const int bt = s >> 3;
    const int rowBase = (s & 7) * 128;
    const int lane = tid & 63, wave = tid >> 6;
    const int lx = lane & 15, quad = lane >> 4;
    const int swz = (lx & 7) << 3;               // Ps short-index XOR swizzle

    // Q fragments straight from global (read once, reused over all 16 ct).
    const unsigned short* qg = qb + ((size_t)bt * BN + rowBase) * FD;
    s8v aq[2][4];
    #pragma unroll
    for (int rg = 0; rg < 2; ++rg)
        #pragma unroll
        for (int t4 = 0; t4 < 4; ++t4)
            aq[rg][t4] = *(const s8v*)(qg + (size_t)(rg * 64 + wave * 16 + lx) * FD + t4 * 32 + quad * 8);

    f4v O[2][8];
    #pragma unroll
    for (int rg = 0; rg < 2; ++rg)
        for (int gg = 0; gg < 8; ++gg) O[rg][gg] = (f4v){0.f, 0.f, 0.f, 0.f};
    float mrow[2] = {-1e30f, -1e30f};
    float lrow[2] = {0.f, 0.f};

    const unsigned short* kgbase = kb + (size_t)bt * BN * FD;
    const unsigned short* vgbase = vtb + (size_t)bt * FD * BN;

    for (int ct = 0; ct < 16; ++ct) {
        __syncthreads();
        const unsigned short* kg = kgbase + (size_t)ct * 64 * FD;
        #pragma unroll
        for (int i = 0; i < 4; ++i) {
            int idx = i * 256 + tid, r = idx >> 4, c8 = idx & 15;
            *(int4*)(&Ks[r * 136 + c8 * 8]) = *(const int4*)(kg + r * FD + c8 * 8);
        }
        #pragma unroll
        for (int i = 0; i < 4; ++i) {
            int idx = i * 256 + tid, r = idx >> 3, c8 = idx & 7;
            *(int4*)(&Vts[r * 72 + c8 * 8]) = *(const int4*)(vgbase + (size_t)r * BN + ct * 64 + c8 * 8);
        }
        __syncthreads();

        #pragma unroll
        for (int rg = 0; rg < 2; ++rg) {
            // QK^T swapped: K as A, Q as B  ->  e[n4][r] = S[q=lx][n4*16+quad*4+r]
            f4v e[4];
            #pragma unroll
            for (int n4 = 0; n4 < 4; ++n4) {
                f4v acc = (f4v){0.f, 0.f, 0.f, 0.f};
                #pragma unroll
                for (int t4 = 0; t4 < 4; ++t4) {
                    s8v bk = *(const s8v*)(&Ks[(n4 * 16 + lx) * 136 + t4 * 32 + quad * 8]);
                    acc = __builtin_amdgcn_mfma_f32_16x16x32_bf16(bk, aq[rg][t4], acc, 0, 0, 0);
                }
                #pragma unroll
                for (int r = 0; r < 4; ++r) acc[r] *= SCALE;
                e[n4] = acc;
            }
            // lane-local max tree + 2 cross-quad shuffles
            float t0 = fmaxf(fmaxf(e[0][0], e[0][1]), fmaxf(e[0][2], e[0][3]));
            float t1 = fmaxf(fmaxf(e[1][0], e[1][1]), fmaxf(e[1][2], e[1][3]));
            float t2 = fmaxf(fmaxf(e[2][0], e[2][1]), fmaxf(e[2][2], e[2][3]));
            float t3 = fmaxf(fmaxf(e[3][0], e[3][1]), fmaxf(e[3][2], e[3][3]));
            float tm = fmaxf(fmaxf(t0, t1), fmaxf(t2, t3));
            tm = fmaxf(tm, __shfl_xor(tm, 16, 64));
            tm = fmaxf(tm, __shfl_xor(tm, 32, 64));
            float mo = mrow[rg];
            float mn = fmaxf(mo, tm);
            mrow[rg] = mn;
            float ps0 = 0.f, ps1 = 0.f, ps2 = 0.f, ps3 = 0.f;
            #pragma unroll
            for (int n4 = 0; n4 < 4; ++n4) {
                float p0 = __expf(e[n4][0] - mn);
                float p1 = __expf(e[n4][1] - mn);
                float p2 = __expf(e[n4][2] - mn);
                float p3 = __expf(e[n4][3] - mn);
                e[n4][0] = p0; e[n4][1] = p1; e[n4][2] = p2; e[n4][3] = p3;
                ps0 += p0; ps1 += p1; ps2 += p2; ps3 += p3;
            }
            float ps = (ps0 + ps1) + (ps2 + ps3);
            ps += __shfl_xor(ps, 16, 64);
            ps += __shfl_xor(ps, 32, 64);
            if (tm > mo) {                     // exact: alpha==1 when not taken
                float alpha = __expf(mo - mn);
                lrow[rg] = lrow[rg] * alpha + ps;
                #pragma unroll
                for (int gg = 0; gg < 8; ++gg)
                    for (int r = 0; r < 4; ++r) O[rg][gg][r] *= alpha;
            } else {
                lrow[rg] += ps;
            }
            // pack P (bf16x2) and transpose via tiny wave-private swizzled LDS
            #pragma unroll
            for (int n4 = 0; n4 < 4; ++n4) {
                unsigned w0 = (unsigned)f2bf(e[n4][0]) | ((unsigned)f2bf(e[n4][1]) << 16);
                unsigned w1 = (unsigned)f2bf(e[n4][2]) | ((unsigned)f2bf(e[n4][3]) << 16);
                int col = (n4 * 16 + quad * 4) ^ swz;
                uint2 w = {w0, w1};
                *(uint2*)(&Ps[wave][lx * 64 + col]) = w;
            }
            // PV swapped: V as A, P as B  ->  O[f=gg*16+quad*4+r][q=lx]
            #pragma unroll
            for (int k2 = 0; k2 < 2; ++k2) {
                s8v bp = *(const s8v*)(&Ps[wave][lx * 64 + ((k2 * 32 + quad * 8) ^ swz)]);
                #pragma unroll
                for (int gg = 0; gg < 8; ++gg) {
                    s8v bv = *(const s8v*)(&Vts[(gg * 16 + lx) * 72 + k2 * 32 + quad * 8]);
                    O[rg][gg] = __builtin_amdgcn_mfma_f32_16x16x32_bf16(bv, bp, O[rg][gg], 0, 0, 0);
                }
            }
        }
    }
    #pragma unroll
    for (int rg = 0; rg < 2; ++rg) {
        const int qglob = rowBase + rg * 64 + wave * 16 + lx;
        float inv = 1.0f / lrow[rg];
        float* vrow = vi + ((size_t)bt * BN + qglob) * FD;
        #pragma unroll
        for (int gg = 0; gg < 8; ++gg) {
            float4 o4 = make_float4(O[rg][gg][0] * inv, O[rg][gg][1] * inv,
                                    O[rg][gg][2] * inv, O[rg][gg][3] * inv);
            *(float4*)(vrow + gg * 16 + quad * 4) = o4;
        }
    }
}

// ---------------------------------------------------------------------------
// Kernel 7: FF1+gelu+FF2+residual+LayerNorm. Scalar fp32, R12-validated
// (bitwise-exact; at its LDS-issue structural floor).
// ---------------------------------------------------------------------------
__global__ __launch_bounds__(256) void k_ffn(const float* __restrict__ vi,
                                             const float* __restrict__ x,
                                             const float* __restrict__ W1,
                                             const float* __restrict__ b1,
                                             const float* __restrict__ W2,
                                             const float* __restrict__ b2,
                                             const float* __restrict__ g,
                                             const float* __restrict__ lb,
                                             float* __restrict__ out) {
    __shared__ float Qs[64][132];
    __shared__ float KVs[32][132];
    const int tid = threadIdx.x;
    const int bt = blockIdx.y;
    const int rowBase = blockIdx.x * 64;
    const int tx = tid & 15, ty = tid >> 4;       // ty 0..15
    const int r0 = ty * 4;                        // 4 rows per thread

    const float* vb = vi + ((size_t)bt * BN + rowBase) * FD;
    for (int i = 0; i < 8; ++i) {
        int idx = i * 256 + tid;
        int r = idx >> 5, c4 = idx & 31;
        *(float4*)(&Qs[r][c4 * 4]) = *(const float4*)(vb + (size_t)r * FD + c4 * 4);
    }

    float h[4][8];
    {
        float t[4][8] = {};
        #pragma unroll
        for (int ch = 0; ch < 4; ++ch) {
            __syncthreads();
            for (int i = 0; i < 4; ++i) {
                int idx = i * 256 + tid;
                int r = idx >> 5, c4 = idx & 31;
                *(float4*)(&KVs[r][c4 * 4]) = *(const float4*)(W1 + (size_t)(ch * 32 + r) * FD + c4 * 4);
            }
            __syncthreads();
            for (int kk = 0; kk < FD; ++kk) {
                float a0 = Qs[r0 + 0][kk], a1 = Qs[r0 + 1][kk];
                float a2 = Qs[r0 + 2][kk], a3 = Qs[r0 + 3][kk];
                #pragma unroll
                for (int jj = 0; jj < 2; ++jj) {
                    int j = jj + 2 * ch;      // f = tx + 16*j = ch*32 + jj*16 + tx
                    float w = KVs[tx + 16 * jj][kk];
                    t[0][j] += a0 * w;
                    t[1][j] += a1 * w;
                    t[2][j] += a2 * w;
                    t[3][j] += a3 * w;
                }
            }
        }
        #pragma unroll
        for (int j = 0; j < 8; ++j) {
            int f = tx + 16 * j;
            float bj = b1[f];
            #pragma unroll
            for (int rr = 0; rr < 4; ++rr) {
                float z = t[rr][j] + bj;
                h[rr][j] = 0.5f * z * (1.0f + erff(z * GELU_K));
            }
        }
    }
    __syncthreads();
    #pragma unroll
    for (int j = 0; j < 8; ++j)
        #pragma unroll
        for (int rr = 0; rr < 4; ++rr)
            Qs[r0 + rr][tx + 16 * j] = h[rr][j];
    __syncthreads();

    float z[4][8];
    {
        float t[4][8] = {};
        #pragma unroll
        for (int ch = 0; ch < 4; ++ch) {
            __syncthreads();
            for (int i = 0; i < 4; ++i) {
                int idx = i * 256 + tid;
                int r = idx >> 5, c4 = idx & 31;
                *(float4*)(&KVs[r][c4 * 4]) = *(const float4*)(W2 + (size_t)(ch * 32 + r) * FD + c4 * 4);
            }
            __syncthreads();
            for (int kk = 0; kk < FD; ++kk) {
                float a0 = Qs[r0 + 0][kk], a1 = Qs[r0 + 1][kk];
                float a2 = Qs[r0 + 2][kk], a3 = Qs[r0 + 3][kk];
                #pragma unroll
                for (int jj = 0; jj < 2; ++jj) {
                    int j = jj + 2 * ch;
                    float w = KVs[tx + 16 * jj][kk];
                    t[0][j] += a0 * w;
                    t[1][j] += a1 * w;
                    t[2][j] += a2 * w;
                    t[3][j] += a3 * w;
                }
            }
        }
        #pragma unroll
        for (int j = 0; j < 8; ++j) {
            int f = tx + 16 * j;
            float bj = b2[f];
            #pragma unroll
            for (int rr = 0; rr < 4; ++rr) z[rr][j] = t[rr][j] + bj;
        }
    }

    const float* xb = x + ((size_t)bt * BN + rowBase) * FD;
    float res[4][8];
    float sum[4] = {0.f, 0.f, 0.f, 0.f};
    #pragma unroll
    for (int j = 0; j < 8; ++j) {
        int f = tx + 16 * j;
        #pragma unroll
        for (int rr = 0; rr < 4; ++rr) {
            float v = z[rr][j] + xb[(size_t)(r0 + rr) * FD + f];
            res[rr][j] = v;
            sum[rr] += v;
        }
    }
    #pragma unroll
    for (int rr = 0; rr < 4; ++rr)
        for (int s = 1; s < 16; s <<= 1) sum[rr] += __shfl_xor(sum[rr], s, 64);
    float mu[4], q[4] = {0.f, 0.f, 0.f, 0.f};
    #pragma unroll
    for (int rr = 0; rr < 4; ++rr) mu[rr] = sum[rr] * (1.0f / FD);
    #pragma unroll
    for (int j = 0; j < 8; ++j)
        #pragma unroll
        for (int rr = 0; rr < 4; ++rr) {
            float d = res[rr][j] - mu[rr];
            q[rr] += d * d;
        }
    #pragma unroll
    for (int rr = 0; rr < 4; ++rr)
        for (int s = 1; s < 16; s <<= 1) q[rr] += __shfl_xor(q[rr], s, 64);
    float rs[4];
    #pragma unroll
    for (int rr = 0; rr < 4; ++rr) rs[rr] = rsqrtf(q[rr] * (1.0f / FD) + 1e-5f);
    float* ob = out + ((size_t)bt * BN + rowBase) * FD;
    #pragma unroll
    for (int j = 0; j < 8; ++j) {
        int f = tx + 16 * j;
        float gf = g[f], bf = lb[f];
        #pragma unroll
        for (int rr = 0; rr < 4; ++rr)
            ob[(size_t)(r0 + rr) * FD + f] = (res[rr][j] - mu[rr]) * rs[rr] * gf + bf;
    }
}

// ---------------------------------------------------------------------------
extern "C" void kernel_launch(void* const* d_in, const int* in_sizes, int n_in,
                              void* d_out, int out_size, void* d_ws, size_t ws_size,
                              hipStream_t stream) {
    const float* x     = (const float*)d_in[0];
    const float* W_xff = (const float*)d_in[1];
    const float* b_xff = (const float*)d_in[2];
    const float* W_ff1 = (const float*)d_in[3];
    const float* b_ff1 = (const float*)d_in[4];
    const float* W_ff2 = (const float*)d_in[5];
    const float* b_ff2 = (const float*)d_in[6];
    const float* ln_g  = (const float*)d_in[7];
    const float* ln_b  = (const float*)d_in[8];
    float* out = (float*)d_out;

    char* w = (char*)d_ws;
    unsigned short* qb16 = (unsigned short*)w;  w += (size_t)BTN * FD * 2;
    unsigned short* kb16 = (unsigned short*)w;  w += (size_t)BTN * FD * 2;
    unsigned short* vtb  = (unsigned short*)w;  w += (size_t)BTN * FD * 2;
    unsigned short* wxb  = (unsigned short*)w;  w += (size_t)3 * FD * FD * 2;
    // vi aliases the region holding Sv/q32c/k32c/stats: all consumed before
    // k_flash writes vi (stream-ordered). Sv (16.8 MB) lives in the former
    // xb slot (25.2 MB) at the start of the alias region.
    char* alias = w;
    float* vi = (float*)alias;                  // BTN*FD*4 = 50.3 MB
    float* Sv = (float*)alias;                  // BB*BN*BN*4 = 16.8 MB (pre-flash)
    alias += (size_t)BTN * FD * 2;              // (former xb slot)
    float* q32c = (float*)alias;                alias += (size_t)BB * BN * FD * 4;
    float* k32c = (float*)alias;                alias += (size_t)BB * BN * FD * 4;
    float* Mv   = (float*)alias;                alias += (size_t)BB * BN * 4;
    float* Lv   = (float*)alias;                alias += (size_t)BB * BN * 4;
    int* ylast  = (int*)alias;                  alias += 256;   // padded
    float* Mp   = (float*)alias;                alias += (size_t)4 * BB * BN * 4;
    float* Lp   = (float*)alias;                alias += (size_t)4 * BB * BN * 4;
    float* csp  = (float*)alias;                alias += (size_t)8 * BB * BN * 4;
    (void)Mv; (void)Lv;

    k_convw    <<<dim3(192),             256, 0, stream>>>(W_xff, wxb, 3 * FD * FD);
    k_qkv_mfma <<<dim3(BTN / 64),        256, 0, stream>>>(x, wxb, b_xff, qb16, kb16, vtb);
    k_qkv32    <<<dim3(BB * 32, 4),      256, 0, stream>>>(x, W_xff, b_xff, q32c, k32c);
    k_pass1    <<<dim3(32, 4, BB),       256, 0, stream>>>(q32c, k32c, Sv, Mp, Lp);
    k_colsum   <<<dim3(16, 8, BB),       256, 0, stream>>>(Sv, Mp, Lp, csp);
    k_top3     <<<dim3(BB),               64, 0, stream>>>(csp, ylast);
    k_mixup    <<<dim3(FRONT_T, BB),     128, 0, stream>>>(x, W_xff, b_xff, vtb, ylast);
    k_flash    <<<dim3(8, BT),           256, 0, stream>>>(qb16, kb16, vtb, vi);
    k_ffn      <<<dim3(16, BT),          256, 0, stream>>>(vi, x, W_ff1, b_ff1, W_ff2, b_ff2,
                                                           ln_g, ln_b, out);
}